// Round 1
// baseline (176.487 us; speedup 1.0000x reference)
//
#include <hip/hip_runtime.h>

// Problem: y[b,co,h,w] = sum_{ci,k} x[b,ci,h,w+k-1] * wt[co,ci,k]  (zero-pad W)
//          out[b,co,h,w] = y[b,co,(h-1)%28,w]   (jnp.roll +1 on H)
// Shapes: x(128,128,28,28) f32, wt(32,128,3) f32, out(128,32,28,28) f32.
//
// Block = 128 thr = 32 co x 4 h-rows; grid = (7 h-tiles, 128 b) = 896 blocks.
// Cin chunked by 16 through LDS; each thread computes one full 28-wide row.

#define CIN   128
#define COUT  32
#define HH    28
#define WW    28
#define CHUNK 16
#define HROWS 4
#define NTHR  128
#define XPAD  32   // pad 28->32 floats per row: keeps float4 alignment per row

__global__ __launch_bounds__(NTHR) void conv1d_roll(
    const float* __restrict__ x,
    const float* __restrict__ wt,
    float* __restrict__ out)
{
    __shared__ float xsh[CHUNK][HROWS][XPAD];   // 8 KB
    __shared__ float wsh[CHUNK][3][COUT];       // 6 KB, co-contiguous

    const int tid = threadIdx.x;
    const int co  = tid & 31;
    const int hl  = tid >> 5;          // 0..3
    const int ht  = blockIdx.x;        // 0..6
    const int b   = blockIdx.y;        // 0..127
    const int h0  = ht * HROWS;

    float acc[WW];
#pragma unroll
    for (int j = 0; j < WW; ++j) acc[j] = 0.0f;

    const float* xb = x + (size_t)b * CIN * HH * WW;

    for (int c0 = 0; c0 < CIN; c0 += CHUNK) {
        // ---- stage x[b, c0+ci, h0+hr, :] : 16ci * 4rows * 7 float4 = 448 f4 ----
        for (int i = tid; i < CHUNK * HROWS * (WW / 4); i += NTHR) {
            int f   = i % (WW / 4);
            int row = i / (WW / 4);
            int hr  = row & (HROWS - 1);
            int ci  = row >> 2;
            float4 v = *(const float4*)(xb + ((size_t)(c0 + ci) * HH + (h0 + hr)) * WW + f * 4);
            *(float4*)(&xsh[ci][hr][f * 4]) = v;
        }
        // ---- stage weights transposed: wsh[ci][k][co] = wt[co][c0+ci][k] ----
        for (int i = tid; i < CHUNK * 3 * COUT; i += NTHR) {
            int c  = i & 31;
            int r  = i >> 5;
            int k  = r % 3;
            int ci = r / 3;
            wsh[ci][k][c] = wt[((size_t)c * CIN + c0 + ci) * 3 + k];
        }
        __syncthreads();

#pragma unroll 4
        for (int ci = 0; ci < CHUNK; ++ci) {
            const float w0 = wsh[ci][0][co];
            const float w1 = wsh[ci][1][co];
            const float w2 = wsh[ci][2][co];
            float xv[WW];
#pragma unroll
            for (int j = 0; j < WW; ++j) xv[j] = xsh[ci][hl][j];  // 7x ds_read_b128, broadcast
            acc[0] += xv[0] * w1 + xv[1] * w2;                    // w=0 edge (x[-1]=0)
#pragma unroll
            for (int j = 1; j < WW - 1; ++j)
                acc[j] += xv[j - 1] * w0 + xv[j] * w1 + xv[j + 1] * w2;
            acc[WW - 1] += xv[WW - 2] * w0 + xv[WW - 1] * w1;     // w=27 edge (x[28]=0)
        }
        __syncthreads();
    }

    // roll(+1, axis=H): computed row h lands at output row (h+1)%28
    const int h    = h0 + hl;
    const int hout = (h + 1) % HH;
    float* op = out + (((size_t)b * COUT + co) * HH + hout) * WW;
#pragma unroll
    for (int f = 0; f < WW / 4; ++f)
        *(float4*)(op + f * 4) = make_float4(acc[4*f], acc[4*f+1], acc[4*f+2], acc[4*f+3]);
}

extern "C" void kernel_launch(void* const* d_in, const int* in_sizes, int n_in,
                              void* d_out, int out_size, void* d_ws, size_t ws_size,
                              hipStream_t stream) {
    const float* x  = (const float*)d_in[0];
    const float* wt = (const float*)d_in[1];
    float* out = (float*)d_out;
    dim3 grid(HH / HROWS, 128);   // 7 h-tiles x 128 batches = 896 blocks
    conv1d_roll<<<grid, NTHR, 0, stream>>>(x, wt, out);
}

// Round 2
// 93.504 us; speedup vs baseline: 1.8875x; 1.8875x over previous
//
#include <hip/hip_runtime.h>

// y[b,co,h,w] = sum_{ci,kk} x[b,ci,h,w+kk-1] * wt[co,ci,kk]; out[...,h,...] gets row (h-1)
// via hout=(h+1)%28 on the write side.
// GEMM view: C[32 x N] = W[32 x 384] * im2col(x)[384 x N], K ordered k = kk*128 + ci.
// mfma_f32_32x32x16_bf16: A[m=lane&31][k=(lane>>5)*8+j], B[k=(lane>>5)*8+j][n=lane&31],
// C/D: col=lane&31, row=(reg&3)+8*(reg>>2)+4*(lane>>5)   [learn_hip m74/m101 verified]

#define CIN  128
#define COUT 32
#define HH   28
#define WW   28
#define CIP  136   // ci dim padded 128->136: row stride 272B breaks 256B bank aliasing
#define WPD  34    // wp = w+1 in [0,33]; wp=0 and wp>=29 are zero halo

typedef __attribute__((ext_vector_type(8))) short short8;
typedef __attribute__((ext_vector_type(8))) __bf16 bf16x8;
typedef __attribute__((ext_vector_type(16))) float f32x16;

__device__ inline unsigned short f2bf(float f) {
    union { float f; unsigned u; } v; v.f = f;
    return (unsigned short)((v.u + 0x7FFFu + ((v.u >> 16) & 1u)) >> 16);  // RNE
}

// ---- kernel 0: weights -> A-fragment layout wf[s][lane][j], s=0..23, 8 bf16/lane ----
__global__ void build_wfrag(const float* __restrict__ wt, unsigned short* __restrict__ wf) {
    int t = blockIdx.x * 256 + threadIdx.x;            // 24*64*8 = 12288
    if (t >= 24 * 64 * 8) return;
    int j = t & 7, lane = (t >> 3) & 63, s = t >> 9;
    int co = lane & 31;
    int k  = s * 16 + (lane >> 5) * 8 + j;             // global K index
    int kk = k >> 7, ci = k & 127;                     // k = kk*128 + ci
    wf[t] = f2bf(wt[((size_t)co * CIN + ci) * 3 + kk]);
}

// ---- main: one block = (b, h-quad); one wave = one (b,h) 32x28 output tile ----
__global__ __launch_bounds__(256) void conv_mfma(
    const float* __restrict__ x,
    const unsigned short* __restrict__ wf,
    float* __restrict__ out)
{
    __shared__ __align__(16) unsigned short xt[4][WPD][CIP];   // 36,992 B

    const int tid = threadIdx.x;
    const int hq  = blockIdx.x;           // 0..6
    const int b   = blockIdx.y;           // 0..127
    const int h0  = hq * 4;
    const float* xb = x + (size_t)b * CIN * HH * WW;

    // zero the W-halo columns wp in {0, 29..33} for all hl, ci
    for (int i = tid; i < 4 * 6 * CIP; i += 256) {
        int ci = i % CIP; int q = i / CIP;
        int wsel = q % 6, hl = q / 6;
        int wp = (wsel == 0) ? 0 : 28 + wsel;
        xt[hl][wp][ci] = 0;
    }

    // stage x[b, ci, h0+hl, :] -> xt[hl][1+w][ci] (fp32->bf16, transpose to ci-contig)
#pragma unroll
    for (int it = 0; it < 14; ++it) {
        int idx  = tid + it * 256;        // float4 index over 128ci * 4h * 7
        int w4   = idx % 7;
        int rest = idx / 7;
        int hl   = rest & 3;
        int ci   = rest >> 2;
        float4 v = *(const float4*)(xb + ((size_t)ci * HH + (h0 + hl)) * WW + w4 * 4);
        int wp = 1 + w4 * 4;
        xt[hl][wp + 0][ci] = f2bf(v.x);
        xt[hl][wp + 1][ci] = f2bf(v.y);
        xt[hl][wp + 2][ci] = f2bf(v.z);
        xt[hl][wp + 3][ci] = f2bf(v.w);
    }

    // A-fragments: 24 x 16B coalesced loads from ws (L2-resident, 24 KB total)
    const int lane = tid & 63;
    const int hl   = tid >> 6;            // wave id = h row
    short8 afr[24];
#pragma unroll
    for (int s = 0; s < 24; ++s)
        afr[s] = *(const short8*)(wf + (size_t)(s * 64 + lane) * 8);

    __syncthreads();

    const int n    = lane & 31;           // output w (valid < 28)
    const int half = lane >> 5;
    f32x16 acc = {0,0,0,0,0,0,0,0,0,0,0,0,0,0,0,0};

#pragma unroll
    for (int s = 0; s < 24; ++s) {
        int kk  = s >> 3;                       // uniform kernel tap per step
        int cib = (s & 7) * 16 + half * 8;      // lane's 8 consecutive ci
        short8 bfr = *(const short8*)&xt[hl][n + kk][cib];
        acc = __builtin_amdgcn_mfma_f32_32x32x16_bf16(
            __builtin_bit_cast(bf16x8, afr[s]),
            __builtin_bit_cast(bf16x8, bfr), acc, 0, 0, 0);
    }

    // epilogue: roll(+1) folded into hout; lanes n>=28 are pad columns, dropped
    if (n < WW) {
        const int hout = (h0 + hl + 1) % HH;
#pragma unroll
        for (int r = 0; r < 16; ++r) {
            int co = (r & 3) + 8 * (r >> 2) + 4 * half;
            out[(((size_t)b * COUT + co) * HH + hout) * WW + n] = acc[r];
        }
    }
}

extern "C" void kernel_launch(void* const* d_in, const int* in_sizes, int n_in,
                              void* d_out, int out_size, void* d_ws, size_t ws_size,
                              hipStream_t stream) {
    const float* x  = (const float*)d_in[0];
    const float* wt = (const float*)d_in[1];
    float* out = (float*)d_out;
    unsigned short* wf = (unsigned short*)d_ws;    // uses 24,576 B of scratch

    build_wfrag<<<48, 256, 0, stream>>>(wt, wf);
    dim3 grid(HH / 4, 128);                        // 7 x 128 = 896 blocks, 4 waves each
    conv_mfma<<<grid, 256, 0, stream>>>(x, wf, out);
}